// Round 6
// baseline (190.255 us; speedup 1.0000x reference)
//
#include <hip/hip_runtime.h>
#include <hip/hip_bf16.h>
#include <stdint.h>

// Problem constants (fixed by the reference)
constexpr int Bv = 16, Nv = 5, Kv = 5, Cv = 512, DKv = 128, DVv = 128, HWv = 256;
constexpr int NSUP = Bv * Nv * Kv;    // 400 support slabs
constexpr int NSLAB = NSUP + Bv;      // + 16 query slabs

typedef __attribute__((ext_vector_type(8))) short bf16x8;
typedef __attribute__((ext_vector_type(4))) float f32x4;

static __device__ __forceinline__ unsigned short f2b(float x) {
  __hip_bfloat16 h = __float2bfloat16(x);
  return *reinterpret_cast<unsigned short*>(&h);
}

// ---------------------------------------------------------------------------
// prep: fused {cvt_w (WbF frag-major), zero(out)}. grid 65.
// (query slabs are consumed directly as fp32 by proj -> cvt_x deleted)
// ---------------------------------------------------------------------------
__global__ __launch_bounds__(256) void prep_kernel(
    const float* __restrict__ w_qk, const float* __restrict__ w_v,
    unsigned short* __restrict__ WbF, float* __restrict__ out, int out_n) {
  const int bid = blockIdx.x;
  const int tid = threadIdx.x;
  if (bid < 64) {
    // WbF fragment-major: [h][kt][ks][nb][lane][8]
    int gidx = bid * 256 + tid;
    int l = gidx & 63;
    int nb = (gidx >> 6) & 7;
    int ks = (gidx >> 9) & 1;
    int kt = (gidx >> 10) & 7;
    int h = (gidx >> 13) & 1;
    int row = nb * 16 + (l & 15);
    int c0 = kt * 64 + ks * 32 + (l >> 4) * 8;
    const float* src = (h ? w_v : w_qk) + (size_t)row * Cv + c0;
    float4 a = *(const float4*)src;
    float4 b = *(const float4*)(src + 4);
    union { unsigned short u[8]; uint4 v; } t;
    t.u[0] = f2b(a.x); t.u[1] = f2b(a.y); t.u[2] = f2b(a.z); t.u[3] = f2b(a.w);
    t.u[4] = f2b(b.x); t.u[5] = f2b(b.y); t.u[6] = f2b(b.z); t.u[7] = f2b(b.w);
    *(uint4*)(WbF + (size_t)gidx * 8) = t.v;
  } else {
    if (tid < out_n) out[tid] = 0.0f;
  }
}

// ---------------------------------------------------------------------------
// proj_all (round-23: WAVE-INDEPENDENT, BARRIER-FREE MAIN LOOP).
//  Each wave owns a DISJOINT 16-pix column strip (pix = wid*16 + lane&15)
//  and computes 16 pix x 256 oc (K AND V): acc[16] (64 AGPR).
//  A-frag loaded DIRECTLY from global fp32 (lane&15=pix, lane>>4=k-group —
//  the verified A-frag mapping), cvt in-reg; B = W-frag from L2-resident
//  WbF. No LDS / no barriers in the loop; 2-deep register staging
//  (aload(kt+2) after converting tile kt). Reads are fully disjoint
//  (supports streamed exactly once — unlike round-21's 4x amplification);
//  __launch_bounds__(256,3) keeps ~150 VGPR unstarved.
//  Epilogue: verified bounce layouts + copy-out loops (bytes unchanged).
//   bid < 1600: support (s=bid>>2, pixq=bid&3).  bid >= 1600: query.
// ---------------------------------------------------------------------------
__global__ __launch_bounds__(256, 3) void proj_all_kernel(
    const float* __restrict__ supports, const float* __restrict__ query,
    const unsigned short* __restrict__ WbF,
    unsigned short* __restrict__ KbF, unsigned short* __restrict__ VbF,
    unsigned short* __restrict__ Qb, float* __restrict__ QVf) {
  __shared__ __align__(16) char smem[18432];
  const int bid = blockIdx.x;
  const int t = threadIdx.x;
  const int lane = t & 63, wid = t >> 6;
  const int l15 = lane & 15, g = lane >> 4;

  const bool is_sup = bid < 1600;
  const int s = is_sup ? (bid >> 2) : 0;
  const int sq = is_sup ? 0 : ((bid - 1600) >> 2);
  const int pixq = is_sup ? (bid & 3) : ((bid - 1600) & 3);
  // Wave's private 16-pix strip base (includes lane's pixel).
  const float* __restrict__ Xs =
      (is_sup ? supports + (size_t)s * Cv * HWv : query + (size_t)sq * Cv * HWv) +
      pixq * 64 + wid * 16 + l15;

  f32x4 acc[16] = {};   // n<8: K/Q half (oc=n*16+l15); n>=8: V half

  float b0[16], b1[16];
  // 16 scalar fp32 loads: c = kt*64 + half*32 + g*8 + j (A-frag k-mapping).
  auto aload = [&](int kt, float* f) {
#pragma unroll
    for (int half = 0; half < 2; ++half)
#pragma unroll
      for (int j = 0; j < 8; ++j)
        f[half * 8 + j] = Xs[(size_t)(kt * 64 + half * 32 + g * 8 + j) * HWv];
  };

  aload(0, b0);
  aload(1, b1);

#pragma unroll
  for (int kt = 0; kt < 8; ++kt) {
    float* fC = (kt & 1) ? b1 : b0;
    // Convert tile kt to A-frags FIRST (frees fC), then refill with kt+2.
    union { unsigned short u[8]; bf16x8 v; } x0, x1;
#pragma unroll
    for (int j = 0; j < 8; ++j) { x0.u[j] = f2b(fC[j]); x1.u[j] = f2b(fC[8 + j]); }
    if (kt < 6) aload(kt + 2, fC);
#pragma unroll
    for (int ks = 0; ks < 2; ++ks) {
      const bf16x8 xf = ks ? x1.v : x0.v;
#pragma unroll
      for (int h = 0; h < 2; ++h) {
        bf16x8 Bf[8];
#pragma unroll
        for (int n = 0; n < 8; ++n)
          Bf[n] = *(const bf16x8*)(
              WbF + (size_t)((((h * 8 + kt) * 2 + ks) * 8 + n) * 64 + lane) * 8);
#pragma unroll
        for (int n = 0; n < 8; ++n)
          acc[h * 8 + n] = __builtin_amdgcn_mfma_f32_16x16x32_bf16(
              xf, Bf[n], acc[h * 8 + n], 0, 0, 0);
      }
    }
  }

  // D-map (m89/m91): oc = n*16 + (lane&15), pix = wid*16 + (lane>>4)*4 + r.
  const int pixl = wid * 16 + g * 4;

  if (is_sup) {
    unsigned short* bounce = (unsigned short*)smem;
    // ---- K half (acc[0..7]) -> bounce[pix(64)][140]; waves disjoint rows ----
#pragma unroll
    for (int n = 0; n < 8; ++n) {
      const int dk = n * 16 + l15;
#pragma unroll
      for (int r = 0; r < 4; ++r)
        bounce[(size_t)(pixl + r) * 140 + dk] = f2b(acc[n][r]);
    }
    __syncthreads();
    {
      unsigned short* Kdst = KbF + ((size_t)s * 4 + pixq) * 8192;
#pragma unroll
      for (int i = 0; i < 4; ++i) {
        const int u = i * 256 + t;  // uint4 index [0,1024)
        const int jl15 = u & 15, jg = (u >> 4) & 3, jkc = (u >> 6) & 3,
                  jnc = (u >> 8) & 3;
        const int pixl2 = jnc * 16 + jl15;
        const int dk = jkc * 32 + jg * 8;
        *(uint4*)(Kdst + (size_t)u * 8) = *(const uint4*)(bounce + (size_t)pixl2 * 140 + dk);
      }
    }
    __syncthreads();   // K-bounce reads done before V-bounce overwrite
    // ---- V half (acc[8..15]) -> bounce[dv(128)][72] ----
#pragma unroll
    for (int n = 0; n < 8; ++n) {
      const int dv = n * 16 + l15;
#pragma unroll
      for (int r = 0; r < 4; ++r)
        bounce[(size_t)dv * 72 + pixl + r] = f2b(acc[8 + n][r]);
    }
    __syncthreads();
    {
      unsigned short* Vdst = VbF + ((size_t)s * 4 + pixq) * 8192;
#pragma unroll
      for (int i = 0; i < 4; ++i) {
        const int u = i * 256 + t;
        const int jl15 = u & 15, jg = (u >> 4) & 3, jd = (u >> 6) & 7,
                  jkc2 = (u >> 9) & 1;
        const int dv = jd * 16 + jl15;
        const int nsl = jkc2 * 32 + jg * 8;
        *(uint4*)(Vdst + (size_t)u * 8) = *(const uint4*)(bounce + (size_t)dv * 72 + nsl);
      }
    }
  } else {
    // ---- query epilogue: direct stores (tiny; 16 slabs) ----
#pragma unroll
    for (int n = 0; n < 8; ++n) {
#pragma unroll
      for (int r = 0; r < 4; ++r) {
        const int pix = pixq * 64 + pixl + r;
        Qb[((size_t)sq * HWv + pix) * DKv + n * 16 + l15] = f2b(acc[n][r]);
        QVf[((size_t)sq * HWv + pix) * DVv + n * 16 + l15] = acc[8 + n][r];
      }
    }
  }
}

// ---------------------------------------------------------------------------
// attn_mfma (round-13 verified, best measured): WG = 4 waves x 16 qpix
// (grid 320); 32KB K/V chunk DMA'd once per WG, double-buffered
// global_load_lds; online softmax spans all ns; fused distance epilogue.
// ---------------------------------------------------------------------------
__global__ __launch_bounds__(256) void attn_mfma_kernel(
    const unsigned short* __restrict__ KbF, const unsigned short* __restrict__ VbF,
    const unsigned short* __restrict__ Qb, const float* __restrict__ QVf,
    float* __restrict__ out) {
  __shared__ __align__(16) char smem[74784];
  unsigned short* Klds = (unsigned short*)smem;             // [2][8192]
  unsigned short* Vlds = (unsigned short*)(smem + 32768);   // [2][8192]
  unsigned short* Plds = (unsigned short*)(smem + 65536);   // [4 wave][16][72]
  float* redbuf = (float*)(smem + 74752);                   // [4]

  const int L = blockIdx.x;
  const int bid = (L & 7) * 40 + (L >> 3);
  const int bn = bid >> 2, qh = bid & 3;
  const int b = bn / Nv;
  const int t = threadIdx.x;
  const int l = t & 63, wid = t >> 6;
  const int l15 = l & 15, g = l >> 4;
  const int qpix0 = qh * 64 + wid * 16;
  constexpr float C2 = 0.08838834764831845f * 1.4426950408889634f;

  bf16x8 qa[4];
#pragma unroll
  for (int kc = 0; kc < 4; ++kc)
    qa[kc] = *(const bf16x8*)(
        Qb + ((size_t)(b * HWv + qpix0 + l15)) * DKv + kc * 32 + g * 8);

  f32x4 oacc[8] = {};
  float mrow[4], lrow[4];
#pragma unroll
  for (int r = 0; r < 4; ++r) { mrow[r] = -3e38f; lrow[r] = 0.0f; }

  unsigned short* Pw = Plds + wid * 16 * 72;

  auto dma = [&](int c, int buf) {
    const int s2 = bn * Kv + (c >> 2);
    const int chunk = c & 3;
    const unsigned short* Kc = KbF + ((size_t)s2 * 4 + chunk) * 8192;
    const unsigned short* Vc = VbF + ((size_t)s2 * 4 + chunk) * 8192;
#pragma unroll
    for (int i = 0; i < 4; ++i) {
      const int seg = wid * 4 + i;
      __builtin_amdgcn_global_load_lds(
          (const __attribute__((address_space(1))) void*)(Kc + (size_t)(seg * 64 + l) * 8),
          (__attribute__((address_space(3))) void*)(Klds + (size_t)buf * 8192 + seg * 512),
          16, 0, 0);
      __builtin_amdgcn_global_load_lds(
          (const __attribute__((address_space(1))) void*)(Vc + (size_t)(seg * 64 + l) * 8),
          (__attribute__((address_space(3))) void*)(Vlds + (size_t)buf * 8192 + seg * 512),
          16, 0, 0);
    }
  };

  dma(0, 0);
  __syncthreads();
  for (int c = 0; c < 20; ++c) {
    const int cur = c & 1;
    if (c < 19) dma(c + 1, cur ^ 1);
    const unsigned short* Kc = Klds + (size_t)cur * 8192;
    const unsigned short* Vc = Vlds + (size_t)cur * 8192;

    f32x4 s4[4];
#pragma unroll
    for (int nc = 0; nc < 4; ++nc) {
      f32x4 sv = {};
#pragma unroll
      for (int kc = 0; kc < 4; ++kc) {
        bf16x8 kf = *(const bf16x8*)(Kc + (size_t)((nc * 4 + kc) * 64 + l) * 8);
        sv = __builtin_amdgcn_mfma_f32_16x16x32_bf16(qa[kc], kf, sv, 0, 0, 0);
      }
      s4[nc] = sv;
    }
    float pm[4];
#pragma unroll
    for (int r = 0; r < 4; ++r) {
      float v = s4[0][r];
#pragma unroll
      for (int nc = 1; nc < 4; ++nc) v = fmaxf(v, s4[nc][r]);
      pm[r] = v;
    }
#pragma unroll
    for (int off = 1; off <= 8; off <<= 1)
#pragma unroll
      for (int r = 0; r < 4; ++r) pm[r] = fmaxf(pm[r], __shfl_xor(pm[r], off));
    float sc[4];
#pragma unroll
    for (int r = 0; r < 4; ++r) {
      float mn = fmaxf(mrow[r], pm[r]);
      sc[r] = exp2f(C2 * (mrow[r] - mn));
      mrow[r] = mn;
      lrow[r] *= sc[r];
    }
#pragma unroll
    for (int d = 0; d < 8; ++d)
#pragma unroll
      for (int r = 0; r < 4; ++r) oacc[d][r] *= sc[r];
#pragma unroll
    for (int nc = 0; nc < 4; ++nc)
#pragma unroll
      for (int r = 0; r < 4; ++r) {
        float p = exp2f(C2 * (s4[nc][r] - mrow[r]));
        lrow[r] += p;
        Pw[(size_t)(g * 4 + r) * 72 + nc * 16 + l15] = f2b(p);
      }
#pragma unroll
    for (int kc2 = 0; kc2 < 2; ++kc2) {
      bf16x8 pa = *(const bf16x8*)(Pw + (size_t)l15 * 72 + kc2 * 32 + g * 8);
#pragma unroll
      for (int d = 0; d < 8; ++d) {
        bf16x8 vf = *(const bf16x8*)(Vc + (size_t)((kc2 * 8 + d) * 64 + l) * 8);
        oacc[d] = __builtin_amdgcn_mfma_f32_16x16x32_bf16(pa, vf, oacc[d], 0, 0, 0);
      }
    }
    __syncthreads();
  }

#pragma unroll
  for (int off = 1; off <= 8; off <<= 1)
#pragma unroll
    for (int r = 0; r < 4; ++r) lrow[r] += __shfl_xor(lrow[r], off);
  float linv[4];
#pragma unroll
  for (int r = 0; r < 4; ++r) linv[r] = 1.0f / lrow[r];

  float part = 0.0f;
#pragma unroll
  for (int d = 0; d < 8; ++d)
#pragma unroll
    for (int r = 0; r < 4; ++r) {
      float o = oacc[d][r] * linv[r];
      float qv = QVf[((size_t)(b * HWv + qpix0 + g * 4 + r)) * DVv + d * 16 + l15];
      float df = qv - o;
      part += df * df;
    }
#pragma unroll
  for (int off = 1; off <= 32; off <<= 1) part += __shfl_xor(part, off);
  if (l == 0) redbuf[wid] = part;
  __syncthreads();
  if (t == 0) {
    float tot = redbuf[0] + redbuf[1] + redbuf[2] + redbuf[3];
    atomicAdd(out + bn, -tot * (1.0f / HWv));
  }
}

// ---------------------------------------------------------------------------
extern "C" void kernel_launch(void* const* d_in, const int* in_sizes, int n_in,
                              void* d_out, int out_size, void* d_ws, size_t ws_size,
                              hipStream_t stream) {
  const float* query = (const float*)d_in[0];     // [B, C, H, W]
  const float* supports = (const float*)d_in[1];  // [B, N, K, C, H, W]
  const float* w_qk = (const float*)d_in[2];      // [DK, C]
  const float* w_v = (const float*)d_in[3];       // [DV, C]
  float* out = (float*)d_out;                     // [B, N]

  const size_t sz_kb = (size_t)NSUP * 4 * 8192 * 2;
  const size_t sz_vb = (size_t)NSUP * 4 * 8192 * 2;
  const size_t sz_qb = (size_t)Bv * HWv * DKv * 2;
  const size_t sz_qvf = (size_t)Bv * HWv * DVv * 4;
  const size_t sz_xb = (size_t)NSLAB * HWv * Cv * 2;  // (unused; layout stability)
  const size_t sz_wb = (size_t)256 * Cv * 2;          // (unused; layout stability)

  char* p = (char*)d_ws;
  unsigned short* KbF = (unsigned short*)p;           p += sz_kb;
  unsigned short* VbF = (unsigned short*)p;           p += sz_vb;
  unsigned short* Qb = (unsigned short*)p;            p += sz_qb;
  float* QVf = (float*)p;                             p += sz_qvf;
  p += sz_xb;  // (old Xb slot, unused)
  p += sz_wb;  // (old row-major Wb slot, unused)
  unsigned short* WbF = (unsigned short*)p;

  prep_kernel<<<65, 256, 0, stream>>>(w_qk, w_v, WbF, out, out_size);
  proj_all_kernel<<<1664, 256, 0, stream>>>(supports, query, WbF, KbF, VbF, Qb, QVf);
  attn_mfma_kernel<<<Bv * Nv * 4, 256, 0, stream>>>(KbF, VbF, Qb, QVf, out);
}

// Round 7
// 137.240 us; speedup vs baseline: 1.3863x; 1.3863x over previous
//
#include <hip/hip_runtime.h>
#include <hip/hip_bf16.h>
#include <stdint.h>

// Problem constants (fixed by the reference)
constexpr int Bv = 16, Nv = 5, Kv = 5, Cv = 512, DKv = 128, DVv = 128, HWv = 256;
constexpr int NSUP = Bv * Nv * Kv;    // 400 support slabs
constexpr int NSLAB = NSUP + Bv;      // + 16 query slabs

typedef __attribute__((ext_vector_type(8))) short bf16x8;
typedef __attribute__((ext_vector_type(4))) float f32x4;

static __device__ __forceinline__ unsigned short f2b(float x) {
  __hip_bfloat16 h = __float2bfloat16(x);
  return *reinterpret_cast<unsigned short*>(&h);
}

#define SB0() __builtin_amdgcn_sched_barrier(0)
#define BARRIER() __builtin_amdgcn_s_barrier()
#define WAITLGKM0() asm volatile("s_waitcnt lgkmcnt(0)" ::: "memory")

// ---------------------------------------------------------------------------
// prep: fused {cvt_w (WbF frag-major), cvt_x (query slabs), zero(out)}.
// grid 577: bid 0-63 WbF, 64-575 cvt_x, 576 zero.
// ---------------------------------------------------------------------------
__global__ __launch_bounds__(256) void prep_kernel(
    const float* __restrict__ query, const float* __restrict__ w_qk,
    const float* __restrict__ w_v, unsigned short* __restrict__ WbF,
    unsigned short* __restrict__ Xb, float* __restrict__ out, int out_n) {
  __shared__ unsigned short lds[64][68];
  const int bid = blockIdx.x;
  const int tid = threadIdx.x;
  if (bid < 64) {
    // WbF fragment-major: [h][kt][ks][nb][lane][8]
    int gidx = bid * 256 + tid;
    int l = gidx & 63;
    int nb = (gidx >> 6) & 7;
    int ks = (gidx >> 9) & 1;
    int kt = (gidx >> 10) & 7;
    int h = (gidx >> 13) & 1;
    int row = nb * 16 + (l & 15);
    int c0 = kt * 64 + ks * 32 + (l >> 4) * 8;
    const float* src = (h ? w_v : w_qk) + (size_t)row * Cv + c0;
    float4 a = *(const float4*)src;
    float4 b = *(const float4*)(src + 4);
    union { unsigned short u[8]; uint4 v; } t;
    t.u[0] = f2b(a.x); t.u[1] = f2b(a.y); t.u[2] = f2b(a.z); t.u[3] = f2b(a.w);
    t.u[4] = f2b(b.x); t.u[5] = f2b(b.y); t.u[6] = f2b(b.z); t.u[7] = f2b(b.w);
    *(uint4*)(WbF + (size_t)gidx * 8) = t.v;
  } else if (bid < 576) {
    // cvt_x for query slabs: fp32 [c][pix] -> bf16 Xb[s][pix][c]
    const int blk = bid - 64;
    const int s = NSUP + (blk >> 5);
    const int tq = blk & 31;
    const int cb = tq >> 2, pb = tq & 3;
    const int c0 = cb * 64, p0 = pb * 64;
    const float* __restrict__ X = query + (size_t)(s - NSUP) * Cv * HWv;
#pragma unroll
    for (int r = 0; r < 4; ++r) {
      int cl = (tid >> 4) + r * 16;
      int pl = (tid & 15) * 4;
      float4 v = *(const float4*)(X + (size_t)(c0 + cl) * HWv + p0 + pl);
      ushort4 u;
      u.x = f2b(v.x); u.y = f2b(v.y); u.z = f2b(v.z); u.w = f2b(v.w);
      *(ushort4*)&lds[cl][pl] = u;
    }
    __syncthreads();
    const int pl2 = tid >> 2;
    const int q0 = (tid & 3) * 16;
    union { unsigned short u[16]; uint4 v4[2]; } tmp;
#pragma unroll
    for (int jj = 0; jj < 16; ++jj) {
      int j = (jj + pl2) & 15;
      tmp.u[j] = lds[q0 + j][pl2];
    }
    unsigned short* dst = Xb + ((size_t)s * HWv + p0 + pl2) * Cv + c0 + q0;
    *(uint4*)dst = tmp.v4[0];
    *((uint4*)dst + 1) = tmp.v4[1];
  } else {
    if (tid < out_n) out[tid] = 0.0f;
  }
}

// ---------------------------------------------------------------------------
// proj_all (round-24: VMCNT-ORDER FIX on the round-22 structure).
//  Identical to round-22 (reg-transpose staging, one barrier/kt, quadrant
//  waves, 2-deep fA/fB) EXCEPT load-issue order inside each phase:
//  Bf (L2, WbF) loads are issued BEFORE the HBM staging loads. vmcnt
//  retires in issue order, so previously the MFMA's wait on Bf (newest)
//  drained the 16 just-issued HBM staging loads EVERY phase (~900 cyc
//  exposed). Now MFMA waits vmcnt(16): Bf retired, staging stays in
//  flight across MFMA + awrite + barrier. Same fix in the query path
//  (Bf before dmaQ; barrier wait vmcnt(2) not 0).
//   bid < 1600: support (s=bid>>2, pixq=bid&3).  bid >= 1600: query.
// ---------------------------------------------------------------------------
__global__ __launch_bounds__(256, 3) void proj_all_kernel(
    const float* __restrict__ supports, const unsigned short* __restrict__ WbF,
    unsigned short* __restrict__ KbF, unsigned short* __restrict__ VbF,
    const unsigned short* __restrict__ Xb, unsigned short* __restrict__ Qb,
    float* __restrict__ QVf) {
  __shared__ __align__(16) char smem[32768];
  const int bid = blockIdx.x;
  const int t = threadIdx.x;
  const int lane = t & 63, wid = t >> 6;
  const int wc = wid & 3;           // quadrant: 0,1 -> K/Q half; 2,3 -> V half
  const int hsel = wc >> 1;         // 0: w_qk, 1: w_v
  const int nq = wc & 1;            // 64-col half within hsel
  const int l15 = lane & 15, g = lane >> 4;

  f32x4 acc[4][4] = {};

  if (bid < 1600) {
    // ---------------- support path ----------------
    const int s = bid >> 2;
    const int pixq = bid & 3;
    unsigned short* X0 = (unsigned short*)smem;           // [64 pix][64 c] swz 8KB
    unsigned short* X1 = (unsigned short*)(smem + 8192);
    const float* __restrict__ Xs = supports + (size_t)s * Cv * HWv + pixq * 64;
    const int slot0 = wid, slot1 = wid + 4;

    float fA[16], fB[16];
    // issue 16 coalesced scalar loads: lane = pix, c = kt*64 + slot*8 + j
    auto aload = [&](int kt, float* f) {
#pragma unroll
      for (int j = 0; j < 8; ++j)
        f[j] = Xs[(size_t)(kt * 64 + slot0 * 8 + j) * HWv + lane];
#pragma unroll
      for (int j = 0; j < 8; ++j)
        f[8 + j] = Xs[(size_t)(kt * 64 + slot1 * 8 + j) * HWv + lane];
    };
    // cvt + swizzled write (consumes f; compiler inserts the vmcnt waits)
    auto awrite = [&](const float* f, unsigned short* dstX) {
      union { unsigned short u[8]; uint4 q; } pk;
#pragma unroll
      for (int j = 0; j < 8; ++j) pk.u[j] = f2b(f[j]);
      *(uint4*)((char*)dstX + lane * 128 + ((slot0 ^ (lane & 7)) * 16)) = pk.q;
#pragma unroll
      for (int j = 0; j < 8; ++j) pk.u[j] = f2b(f[8 + j]);
      *(uint4*)((char*)dstX + lane * 128 + ((slot1 ^ (lane & 7)) * 16)) = pk.q;
    };

    // Prologue: tiles 0,1 in flight; stage tile 0.
    aload(0, fA);
    aload(1, fB);
    awrite(fA, X0);
    WAITLGKM0(); SB0(); BARRIER(); SB0();

#pragma unroll
    for (int kt = 0; kt < 8; ++kt) {
      const int cur = kt & 1;
      const unsigned short* Xc = cur ? X1 : X0;
      unsigned short* Xn = cur ? X0 : X1;
      // (1) Bf (L2) loads FIRST -> oldest in the vmem queue.
      bf16x8 Bf[2][4];
#pragma unroll
      for (int ks = 0; ks < 2; ++ks)
#pragma unroll
        for (int n = 0; n < 4; ++n)
          Bf[ks][n] = *(const bf16x8*)(
              WbF + (size_t)((((hsel * 8 + kt) * 2 + ks) * 8 + nq * 4 + n) * 64 + lane) * 8);
      SB0();
      // (2) HBM staging loads AFTER -> MFMA's Bf wait leaves them in flight.
      if (kt < 6) aload(kt + 2, cur ? fB : fA);
      SB0();
      // (3) MFMA blocks (A from LDS; Bf already queued ahead of staging).
#pragma unroll
      for (int ks = 0; ks < 2; ++ks) {
        const int sx = ((ks * 4 + g) ^ (l15 & 7)) * 16;
        bf16x8 A[4];
#pragma unroll
        for (int m = 0; m < 4; ++m)
          A[m] = *(const bf16x8*)((const char*)Xc + (m * 16 + l15) * 128 + sx);
#pragma unroll
        for (int m = 0; m < 4; ++m)
#pragma unroll
          for (int n = 0; n < 4; ++n)
            acc[m][n] = __builtin_amdgcn_mfma_f32_16x16x32_bf16(A[m], Bf[ks][n],
                                                                acc[m][n], 0, 0, 0);
      }
      if (kt < 7) {
        awrite(cur ? fA : fB, Xn);             // tile kt+1 (loaded a full it ago)
        WAITLGKM0(); SB0(); BARRIER(); SB0();  // writes visible; single barrier
      }
    }

    // Epilogue. C/D map: col=lane&15, row=(lane>>4)*4+reg (m89/m91).
    __syncthreads();   // all MFMA reads of X done before bounce overwrites
    unsigned short* bounce = (unsigned short*)smem;
    // ---- K half (waves wc<2) -> bounce[pix(64)][140] ----
    if (hsel == 0) {
#pragma unroll
      for (int m = 0; m < 4; ++m) {
        const int pr = m * 16 + g * 4;
#pragma unroll
        for (int n = 0; n < 4; ++n) {
          const int dk = nq * 64 + n * 16 + l15;
#pragma unroll
          for (int r = 0; r < 4; ++r)
            bounce[(size_t)(pr + r) * 140 + dk] = f2b(acc[m][n][r]);
        }
      }
    }
    __syncthreads();
    {
      unsigned short* Kdst = KbF + ((size_t)s * 4 + pixq) * 8192;
#pragma unroll
      for (int i = 0; i < 4; ++i) {
        const int u = i * 256 + t;  // uint4 index [0,1024)
        const int jl15 = u & 15, jg = (u >> 4) & 3, jkc = (u >> 6) & 3,
                  jnc = (u >> 8) & 3;
        const int pixl = jnc * 16 + jl15;
        const int dk = jkc * 32 + jg * 8;
        *(uint4*)(Kdst + (size_t)u * 8) = *(const uint4*)(bounce + (size_t)pixl * 140 + dk);
      }
    }
    __syncthreads();   // K-bounce reads done before V-bounce overwrite
    // ---- V half (waves wc>=2) -> bounce[dv(128)][72] ----
    if (hsel == 1) {
#pragma unroll
      for (int m = 0; m < 4; ++m) {
        const int pr = m * 16 + g * 4;
#pragma unroll
        for (int n = 0; n < 4; ++n) {
          const int dv = nq * 64 + n * 16 + l15;
#pragma unroll
          for (int r = 0; r < 4; ++r)
            bounce[(size_t)dv * 72 + pr + r] = f2b(acc[m][n][r]);
        }
      }
    }
    __syncthreads();
    {
      unsigned short* Vdst = VbF + ((size_t)s * 4 + pixq) * 8192;
#pragma unroll
      for (int i = 0; i < 4; ++i) {
        const int u = i * 256 + t;
        const int jl15 = u & 15, jg = (u >> 4) & 3, jd = (u >> 6) & 7,
                  jkc2 = (u >> 9) & 1;
        const int dv = jd * 16 + jl15;
        const int nsl = jkc2 * 32 + jg * 8;
        *(uint4*)(Vdst + (size_t)u * 8) = *(const uint4*)(bounce + (size_t)dv * 72 + nsl);
      }
    }
  } else {
    // ---------------- query path (Q + QV, quadrant waves) ----------------
    const int r0 = bid - 1600;       // 0..63
    const int sq = r0 >> 2;
    const int pixq = r0 & 3;
    unsigned short* Xt2 = (unsigned short*)smem;   // [4][64 pix][64 c] swz, 32KB
    const unsigned short* __restrict__ Xq =
        Xb + ((size_t)(NSUP + sq) * HWv + pixq * 64) * Cv;

    // bf16 A-tile staged with PRE-SWIZZLED SOURCE (linear dest = base+lane*16).
    auto dmaQ = [&](int kt, int buf) {
#pragma unroll
      for (int i = 0; i < 2; ++i) {
        const int seg = wid * 2 + i;                 // 8 segs of 1KB
        const int row = seg * 8 + (lane >> 3);
        const int srcslot = (lane & 7) ^ ((lane >> 3) & 7);
        const unsigned short* gsrc = Xq + (size_t)row * Cv + kt * 64 + srcslot * 8;
        __builtin_amdgcn_global_load_lds(
            (const __attribute__((address_space(1))) void*)gsrc,
            (__attribute__((address_space(3))) void*)((char*)Xt2 + buf * 8192 + seg * 1024),
            16, 0, 0);
      }
    };

    dmaQ(0, 0);
    dmaQ(1, 1);
    asm volatile("s_waitcnt vmcnt(2)" ::: "memory");
    SB0(); BARRIER(); SB0();
    for (int kt = 0; kt < 8; ++kt) {
      // (1) Bf loads FIRST (oldest in queue).
      bf16x8 Bf[2][4];
#pragma unroll
      for (int ks = 0; ks < 2; ++ks)
#pragma unroll
        for (int n = 0; n < 4; ++n)
          Bf[ks][n] = *(const bf16x8*)(
              WbF + (size_t)((((hsel * 8 + kt) * 2 + ks) * 8 + nq * 4 + n) * 64 + lane) * 8);
      SB0();
      // (2) DMA for kt+2 after.
      if (kt < 6) dmaQ(kt + 2, (kt + 2) & 3);   // buffer last read at MFMA(kt-2)
      SB0();
      const char* Xt = (const char*)Xt2 + (kt & 3) * 8192;
#pragma unroll
      for (int ks = 0; ks < 2; ++ks) {
        const int sx = ((ks * 4 + g) ^ (l15 & 7)) * 16;
        bf16x8 A[4];
#pragma unroll
        for (int m = 0; m < 4; ++m)
          A[m] = *(const bf16x8*)(Xt + (m * 16 + l15) * 128 + sx);
#pragma unroll
        for (int m = 0; m < 4; ++m)
#pragma unroll
          for (int n = 0; n < 4; ++n)
            acc[m][n] = __builtin_amdgcn_mfma_f32_16x16x32_bf16(A[m], Bf[ks][n],
                                                                acc[m][n], 0, 0, 0);
      }
      if (kt < 7) {
        SB0();
        if (kt < 6) {
          asm volatile("s_waitcnt vmcnt(2)" ::: "memory");  // kt+1 landed; kt+2 in flight
        } else {
          asm volatile("s_waitcnt vmcnt(0)" ::: "memory");
        }
        SB0(); BARRIER(); SB0();
      }
    }

    // Direct stores (16 query slabs, tiny). C/D map as above.
#pragma unroll
    for (int m = 0; m < 4; ++m) {
      const int pixr = pixq * 64 + m * 16 + g * 4;
#pragma unroll
      for (int n = 0; n < 4; ++n) {
        const int oc = nq * 64 + n * 16 + l15;
        if (hsel == 0) {
          unsigned short* p = Qb + ((size_t)sq * HWv + pixr) * DKv + oc;
#pragma unroll
          for (int r = 0; r < 4; ++r) p[(size_t)r * DKv] = f2b(acc[m][n][r]);
        } else {
          float* p = QVf + ((size_t)sq * HWv + pixr) * DVv + oc;
#pragma unroll
          for (int r = 0; r < 4; ++r) p[(size_t)r * DVv] = acc[m][n][r];
        }
      }
    }
  }
}

// ---------------------------------------------------------------------------
// attn_mfma (round-13 verified, best measured): WG = 4 waves x 16 qpix
// (grid 320); 32KB K/V chunk DMA'd once per WG, double-buffered
// global_load_lds; online softmax spans all ns; fused distance epilogue.
// ---------------------------------------------------------------------------
__global__ __launch_bounds__(256) void attn_mfma_kernel(
    const unsigned short* __restrict__ KbF, const unsigned short* __restrict__ VbF,
    const unsigned short* __restrict__ Qb, const float* __restrict__ QVf,
    float* __restrict__ out) {
  __shared__ __align__(16) char smem[74784];
  unsigned short* Klds = (unsigned short*)smem;             // [2][8192]
  unsigned short* Vlds = (unsigned short*)(smem + 32768);   // [2][8192]
  unsigned short* Plds = (unsigned short*)(smem + 65536);   // [4 wave][16][72]
  float* redbuf = (float*)(smem + 74752);                   // [4]

  const int L = blockIdx.x;
  const int bid = (L & 7) * 40 + (L >> 3);
  const int bn = bid >> 2, qh = bid & 3;
  const int b = bn / Nv;
  const int t = threadIdx.x;
  const int l = t & 63, wid = t >> 6;
  const int l15 = l & 15, g = l >> 4;
  const int qpix0 = qh * 64 + wid * 16;
  constexpr float C2 = 0.08838834764831845f * 1.4426950408889634f;

  bf16x8 qa[4];
#pragma unroll
  for (int kc = 0; kc < 4; ++kc)
    qa[kc] = *(const bf16x8*)(
        Qb + ((size_t)(b * HWv + qpix0 + l15)) * DKv + kc * 32 + g * 8);

  f32x4 oacc[8] = {};
  float mrow[4], lrow[4];
#pragma unroll
  for (int r = 0; r < 4; ++r) { mrow[r] = -3e38f; lrow[r] = 0.0f; }

  unsigned short* Pw = Plds + wid * 16 * 72;

  auto dma = [&](int c, int buf) {
    const int s2 = bn * Kv + (c >> 2);
    const int chunk = c & 3;
    const unsigned short* Kc = KbF + ((size_t)s2 * 4 + chunk) * 8192;
    const unsigned short* Vc = VbF + ((size_t)s2 * 4 + chunk) * 8192;
#pragma unroll
    for (int i = 0; i < 4; ++i) {
      const int seg = wid * 4 + i;
      __builtin_amdgcn_global_load_lds(
          (const __attribute__((address_space(1))) void*)(Kc + (size_t)(seg * 64 + l) * 8),
          (__attribute__((address_space(3))) void*)(Klds + (size_t)buf * 8192 + seg * 512),
          16, 0, 0);
      __builtin_amdgcn_global_load_lds(
          (const __attribute__((address_space(1))) void*)(Vc + (size_t)(seg * 64 + l) * 8),
          (__attribute__((address_space(3))) void*)(Vlds + (size_t)buf * 8192 + seg * 512),
          16, 0, 0);
    }
  };

  dma(0, 0);
  __syncthreads();
  for (int c = 0; c < 20; ++c) {
    const int cur = c & 1;
    if (c < 19) dma(c + 1, cur ^ 1);
    const unsigned short* Kc = Klds + (size_t)cur * 8192;
    const unsigned short* Vc = Vlds + (size_t)cur * 8192;

    f32x4 s4[4];
#pragma unroll
    for (int nc = 0; nc < 4; ++nc) {
      f32x4 sv = {};
#pragma unroll
      for (int kc = 0; kc < 4; ++kc) {
        bf16x8 kf = *(const bf16x8*)(Kc + (size_t)((nc * 4 + kc) * 64 + l) * 8);
        sv = __builtin_amdgcn_mfma_f32_16x16x32_bf16(qa[kc], kf, sv, 0, 0, 0);
      }
      s4[nc] = sv;
    }
    float pm[4];
#pragma unroll
    for (int r = 0; r < 4; ++r) {
      float v = s4[0][r];
#pragma unroll
      for (int nc = 1; nc < 4; ++nc) v = fmaxf(v, s4[nc][r]);
      pm[r] = v;
    }
#pragma unroll
    for (int off = 1; off <= 8; off <<= 1)
#pragma unroll
      for (int r = 0; r < 4; ++r) pm[r] = fmaxf(pm[r], __shfl_xor(pm[r], off));
    float sc[4];
#pragma unroll
    for (int r = 0; r < 4; ++r) {
      float mn = fmaxf(mrow[r], pm[r]);
      sc[r] = exp2f(C2 * (mrow[r] - mn));
      mrow[r] = mn;
      lrow[r] *= sc[r];
    }
#pragma unroll
    for (int d = 0; d < 8; ++d)
#pragma unroll
      for (int r = 0; r < 4; ++r) oacc[d][r] *= sc[r];
#pragma unroll
    for (int nc = 0; nc < 4; ++nc)
#pragma unroll
      for (int r = 0; r < 4; ++r) {
        float p = exp2f(C2 * (s4[nc][r] - mrow[r]));
        lrow[r] += p;
        Pw[(size_t)(g * 4 + r) * 72 + nc * 16 + l15] = f2b(p);
      }
#pragma unroll
    for (int kc2 = 0; kc2 < 2; ++kc2) {
      bf16x8 pa = *(const bf16x8*)(Pw + (size_t)l15 * 72 + kc2 * 32 + g * 8);
#pragma unroll
      for (int d = 0; d < 8; ++d) {
        bf16x8 vf = *(const bf16x8*)(Vc + (size_t)((kc2 * 8 + d) * 64 + l) * 8);
        oacc[d] = __builtin_amdgcn_mfma_f32_16x16x32_bf16(pa, vf, oacc[d], 0, 0, 0);
      }
    }
    __syncthreads();
  }

#pragma unroll
  for (int off = 1; off <= 8; off <<= 1)
#pragma unroll
    for (int r = 0; r < 4; ++r) lrow[r] += __shfl_xor(lrow[r], off);
  float linv[4];
#pragma unroll
  for (int r = 0; r < 4; ++r) linv[r] = 1.0f / lrow[r];

  float part = 0.0f;
#pragma unroll
  for (int d = 0; d < 8; ++d)
#pragma unroll
    for (int r = 0; r < 4; ++r) {
      float o = oacc[d][r] * linv[r];
      float qv = QVf[((size_t)(b * HWv + qpix0 + g * 4 + r)) * DVv + d * 16 + l15];
      float df = qv - o;
      part += df * df;
    }
#pragma unroll
  for (int off = 1; off <= 32; off <<= 1) part += __shfl_xor(part, off);
  if (l == 0) redbuf[wid] = part;
  __syncthreads();
  if (t == 0) {
    float tot = redbuf[0] + redbuf[1] + redbuf[2] + redbuf[3];
    atomicAdd(out + bn, -tot * (1.0f / HWv));
  }
}

// ---------------------------------------------------------------------------
extern "C" void kernel_launch(void* const* d_in, const int* in_sizes, int n_in,
                              void* d_out, int out_size, void* d_ws, size_t ws_size,
                              hipStream_t stream) {
  const float* query = (const float*)d_in[0];     // [B, C, H, W]
  const float* supports = (const float*)d_in[1];  // [B, N, K, C, H, W]
  const float* w_qk = (const float*)d_in[2];      // [DK, C]
  const float* w_v = (const float*)d_in[3];       // [DV, C]
  float* out = (float*)d_out;                     // [B, N]

  const size_t sz_kb = (size_t)NSUP * 4 * 8192 * 2;
  const size_t sz_vb = (size_t)NSUP * 4 * 8192 * 2;
  const size_t sz_qb = (size_t)Bv * HWv * DKv * 2;
  const size_t sz_qvf = (size_t)Bv * HWv * DVv * 4;
  const size_t sz_xb = (size_t)NSLAB * HWv * Cv * 2;
  const size_t sz_wb = (size_t)256 * Cv * 2;  // (kept for layout stability)

  char* p = (char*)d_ws;
  unsigned short* KbF = (unsigned short*)p;           p += sz_kb;
  unsigned short* VbF = (unsigned short*)p;           p += sz_vb;
  unsigned short* Qb = (unsigned short*)p;            p += sz_qb;
  float* QVf = (float*)p;                             p += sz_qvf;
  unsigned short* Xb = (unsigned short*)p;            p += sz_xb;
  p += sz_wb;  // (old row-major Wb slot, unused)
  unsigned short* WbF = (unsigned short*)p;

  prep_kernel<<<577, 256, 0, stream>>>(query, w_qk, w_v, WbF, Xb, out, out_size);
  proj_all_kernel<<<1664, 256, 0, stream>>>(supports, WbF, KbF, VbF, Xb, Qb, QVf);
  attn_mfma_kernel<<<Bv * Nv * 4, 256, 0, stream>>>(KbF, VbF, Qb, QVf, out);
}

// Round 8
// 123.731 us; speedup vs baseline: 1.5376x; 1.1092x over previous
//
#include <hip/hip_runtime.h>
#include <hip/hip_bf16.h>
#include <stdint.h>

// Problem constants (fixed by the reference)
constexpr int Bv = 16, Nv = 5, Kv = 5, Cv = 512, DKv = 128, DVv = 128, HWv = 256;
constexpr int NSUP = Bv * Nv * Kv;    // 400 support slabs
constexpr int NSLAB = NSUP + Bv;      // + 16 query slabs

typedef __attribute__((ext_vector_type(8))) short bf16x8;
typedef __attribute__((ext_vector_type(4))) float f32x4;

static __device__ __forceinline__ unsigned short f2b(float x) {
  __hip_bfloat16 h = __float2bfloat16(x);
  return *reinterpret_cast<unsigned short*>(&h);
}

#define SB0() __builtin_amdgcn_sched_barrier(0)
#define BARRIER() __builtin_amdgcn_s_barrier()
#define WAITLGKM0() asm volatile("s_waitcnt lgkmcnt(0)" ::: "memory")

// ---------------------------------------------------------------------------
// prep: fused {cvt_w (WbF frag-major), cvt_x (query slabs), zero(out)}.
// grid 577: bid 0-63 WbF, 64-575 cvt_x, 576 zero.
// ---------------------------------------------------------------------------
__global__ __launch_bounds__(256) void prep_kernel(
    const float* __restrict__ query, const float* __restrict__ w_qk,
    const float* __restrict__ w_v, unsigned short* __restrict__ WbF,
    unsigned short* __restrict__ Xb, float* __restrict__ out, int out_n) {
  __shared__ unsigned short lds[64][68];
  const int bid = blockIdx.x;
  const int tid = threadIdx.x;
  if (bid < 64) {
    // WbF fragment-major: [h][kt][ks][nb][lane][8]
    int gidx = bid * 256 + tid;
    int l = gidx & 63;
    int nb = (gidx >> 6) & 7;
    int ks = (gidx >> 9) & 1;
    int kt = (gidx >> 10) & 7;
    int h = (gidx >> 13) & 1;
    int row = nb * 16 + (l & 15);
    int c0 = kt * 64 + ks * 32 + (l >> 4) * 8;
    const float* src = (h ? w_v : w_qk) + (size_t)row * Cv + c0;
    float4 a = *(const float4*)src;
    float4 b = *(const float4*)(src + 4);
    union { unsigned short u[8]; uint4 v; } t;
    t.u[0] = f2b(a.x); t.u[1] = f2b(a.y); t.u[2] = f2b(a.z); t.u[3] = f2b(a.w);
    t.u[4] = f2b(b.x); t.u[5] = f2b(b.y); t.u[6] = f2b(b.z); t.u[7] = f2b(b.w);
    *(uint4*)(WbF + (size_t)gidx * 8) = t.v;
  } else if (bid < 576) {
    // cvt_x for query slabs: fp32 [c][pix] -> bf16 Xb[s][pix][c]
    const int blk = bid - 64;
    const int s = NSUP + (blk >> 5);
    const int tq = blk & 31;
    const int cb = tq >> 2, pb = tq & 3;
    const int c0 = cb * 64, p0 = pb * 64;
    const float* __restrict__ X = query + (size_t)(s - NSUP) * Cv * HWv;
#pragma unroll
    for (int r = 0; r < 4; ++r) {
      int cl = (tid >> 4) + r * 16;
      int pl = (tid & 15) * 4;
      float4 v = *(const float4*)(X + (size_t)(c0 + cl) * HWv + p0 + pl);
      ushort4 u;
      u.x = f2b(v.x); u.y = f2b(v.y); u.z = f2b(v.z); u.w = f2b(v.w);
      *(ushort4*)&lds[cl][pl] = u;
    }
    __syncthreads();
    const int pl2 = tid >> 2;
    const int q0 = (tid & 3) * 16;
    union { unsigned short u[16]; uint4 v4[2]; } tmp;
#pragma unroll
    for (int jj = 0; jj < 16; ++jj) {
      int j = (jj + pl2) & 15;
      tmp.u[j] = lds[q0 + j][pl2];
    }
    unsigned short* dst = Xb + ((size_t)s * HWv + p0 + pl2) * Cv + c0 + q0;
    *(uint4*)dst = tmp.v4[0];
    *((uint4*)dst + 1) = tmp.v4[1];
  } else {
    if (tid < out_n) out[tid] = 0.0f;
  }
}

// ---------------------------------------------------------------------------
// proj_all (round-25: REGISTER-UNSTARVE — single change vs round-24).
//  __launch_bounds__(256, 3) -> (256, 2). Theory: the 170-VGPR cap from
//  min-3-waves/EU sat exactly at the kernel's ~164-reg demand, so the
//  allocator serialized the 16 staging loads (issue-few, vmcnt, cvt,
//  reuse) => ~12K-cycle phases (measured VGPR_Count 84 arch + 64 acc).
//  With a 256 budget the ~164-reg allocation still FITS 3 waves/SIMD in
//  HW (3x164 <= 512) — same residency, unstarved schedule, 32 staging
//  loads genuinely in flight. Everything else identical to round-24.
//   bid < 1600: support (s=bid>>2, pixq=bid&3).  bid >= 1600: query.
// ---------------------------------------------------------------------------
__global__ __launch_bounds__(256, 2) void proj_all_kernel(
    const float* __restrict__ supports, const unsigned short* __restrict__ WbF,
    unsigned short* __restrict__ KbF, unsigned short* __restrict__ VbF,
    const unsigned short* __restrict__ Xb, unsigned short* __restrict__ Qb,
    float* __restrict__ QVf) {
  __shared__ __align__(16) char smem[32768];
  const int bid = blockIdx.x;
  const int t = threadIdx.x;
  const int lane = t & 63, wid = t >> 6;
  const int wc = wid & 3;           // quadrant: 0,1 -> K/Q half; 2,3 -> V half
  const int hsel = wc >> 1;         // 0: w_qk, 1: w_v
  const int nq = wc & 1;            // 64-col half within hsel
  const int l15 = lane & 15, g = lane >> 4;

  f32x4 acc[4][4] = {};

  if (bid < 1600) {
    // ---------------- support path ----------------
    const int s = bid >> 2;
    const int pixq = bid & 3;
    unsigned short* X0 = (unsigned short*)smem;           // [64 pix][64 c] swz 8KB
    unsigned short* X1 = (unsigned short*)(smem + 8192);
    const float* __restrict__ Xs = supports + (size_t)s * Cv * HWv + pixq * 64;
    const int slot0 = wid, slot1 = wid + 4;

    float fA[16], fB[16];
    // issue 16 coalesced scalar loads: lane = pix, c = kt*64 + slot*8 + j
    auto aload = [&](int kt, float* f) {
#pragma unroll
      for (int j = 0; j < 8; ++j)
        f[j] = Xs[(size_t)(kt * 64 + slot0 * 8 + j) * HWv + lane];
#pragma unroll
      for (int j = 0; j < 8; ++j)
        f[8 + j] = Xs[(size_t)(kt * 64 + slot1 * 8 + j) * HWv + lane];
    };
    // cvt + swizzled write (consumes f; compiler inserts the vmcnt waits)
    auto awrite = [&](const float* f, unsigned short* dstX) {
      union { unsigned short u[8]; uint4 q; } pk;
#pragma unroll
      for (int j = 0; j < 8; ++j) pk.u[j] = f2b(f[j]);
      *(uint4*)((char*)dstX + lane * 128 + ((slot0 ^ (lane & 7)) * 16)) = pk.q;
#pragma unroll
      for (int j = 0; j < 8; ++j) pk.u[j] = f2b(f[8 + j]);
      *(uint4*)((char*)dstX + lane * 128 + ((slot1 ^ (lane & 7)) * 16)) = pk.q;
    };

    // Prologue: tiles 0,1 in flight; stage tile 0.
    aload(0, fA);
    aload(1, fB);
    awrite(fA, X0);
    WAITLGKM0(); SB0(); BARRIER(); SB0();

#pragma unroll
    for (int kt = 0; kt < 8; ++kt) {
      const int cur = kt & 1;
      const unsigned short* Xc = cur ? X1 : X0;
      unsigned short* Xn = cur ? X0 : X1;
      // (1) Bf (L2) loads FIRST -> oldest in the vmem queue.
      bf16x8 Bf[2][4];
#pragma unroll
      for (int ks = 0; ks < 2; ++ks)
#pragma unroll
        for (int n = 0; n < 4; ++n)
          Bf[ks][n] = *(const bf16x8*)(
              WbF + (size_t)((((hsel * 8 + kt) * 2 + ks) * 8 + nq * 4 + n) * 64 + lane) * 8);
      SB0();
      // (2) HBM staging loads AFTER -> MFMA's Bf wait leaves them in flight.
      if (kt < 6) aload(kt + 2, cur ? fB : fA);
      SB0();
      // (3) MFMA blocks (A from LDS; Bf already queued ahead of staging).
#pragma unroll
      for (int ks = 0; ks < 2; ++ks) {
        const int sx = ((ks * 4 + g) ^ (l15 & 7)) * 16;
        bf16x8 A[4];
#pragma unroll
        for (int m = 0; m < 4; ++m)
          A[m] = *(const bf16x8*)((const char*)Xc + (m * 16 + l15) * 128 + sx);
#pragma unroll
        for (int m = 0; m < 4; ++m)
#pragma unroll
          for (int n = 0; n < 4; ++n)
            acc[m][n] = __builtin_amdgcn_mfma_f32_16x16x32_bf16(A[m], Bf[ks][n],
                                                                acc[m][n], 0, 0, 0);
      }
      if (kt < 7) {
        awrite(cur ? fA : fB, Xn);             // tile kt+1 (loaded a full it ago)
        WAITLGKM0(); SB0(); BARRIER(); SB0();  // writes visible; single barrier
      }
    }

    // Epilogue. C/D map: col=lane&15, row=(lane>>4)*4+reg (m89/m91).
    __syncthreads();   // all MFMA reads of X done before bounce overwrites
    unsigned short* bounce = (unsigned short*)smem;
    // ---- K half (waves wc<2) -> bounce[pix(64)][140] ----
    if (hsel == 0) {
#pragma unroll
      for (int m = 0; m < 4; ++m) {
        const int pr = m * 16 + g * 4;
#pragma unroll
        for (int n = 0; n < 4; ++n) {
          const int dk = nq * 64 + n * 16 + l15;
#pragma unroll
          for (int r = 0; r < 4; ++r)
            bounce[(size_t)(pr + r) * 140 + dk] = f2b(acc[m][n][r]);
        }
      }
    }
    __syncthreads();
    {
      unsigned short* Kdst = KbF + ((size_t)s * 4 + pixq) * 8192;
#pragma unroll
      for (int i = 0; i < 4; ++i) {
        const int u = i * 256 + t;  // uint4 index [0,1024)
        const int jl15 = u & 15, jg = (u >> 4) & 3, jkc = (u >> 6) & 3,
                  jnc = (u >> 8) & 3;
        const int pixl = jnc * 16 + jl15;
        const int dk = jkc * 32 + jg * 8;
        *(uint4*)(Kdst + (size_t)u * 8) = *(const uint4*)(bounce + (size_t)pixl * 140 + dk);
      }
    }
    __syncthreads();   // K-bounce reads done before V-bounce overwrite
    // ---- V half (waves wc>=2) -> bounce[dv(128)][72] ----
    if (hsel == 1) {
#pragma unroll
      for (int m = 0; m < 4; ++m) {
        const int pr = m * 16 + g * 4;
#pragma unroll
        for (int n = 0; n < 4; ++n) {
          const int dv = nq * 64 + n * 16 + l15;
#pragma unroll
          for (int r = 0; r < 4; ++r)
            bounce[(size_t)dv * 72 + pr + r] = f2b(acc[m][n][r]);
        }
      }
    }
    __syncthreads();
    {
      unsigned short* Vdst = VbF + ((size_t)s * 4 + pixq) * 8192;
#pragma unroll
      for (int i = 0; i < 4; ++i) {
        const int u = i * 256 + t;
        const int jl15 = u & 15, jg = (u >> 4) & 3, jd = (u >> 6) & 7,
                  jkc2 = (u >> 9) & 1;
        const int dv = jd * 16 + jl15;
        const int nsl = jkc2 * 32 + jg * 8;
        *(uint4*)(Vdst + (size_t)u * 8) = *(const uint4*)(bounce + (size_t)dv * 72 + nsl);
      }
    }
  } else {
    // ---------------- query path (Q + QV, quadrant waves) ----------------
    const int r0 = bid - 1600;       // 0..63
    const int sq = r0 >> 2;
    const int pixq = r0 & 3;
    unsigned short* Xt2 = (unsigned short*)smem;   // [4][64 pix][64 c] swz, 32KB
    const unsigned short* __restrict__ Xq =
        Xb + ((size_t)(NSUP + sq) * HWv + pixq * 64) * Cv;

    // bf16 A-tile staged with PRE-SWIZZLED SOURCE (linear dest = base+lane*16).
    auto dmaQ = [&](int kt, int buf) {
#pragma unroll
      for (int i = 0; i < 2; ++i) {
        const int seg = wid * 2 + i;                 // 8 segs of 1KB
        const int row = seg * 8 + (lane >> 3);
        const int srcslot = (lane & 7) ^ ((lane >> 3) & 7);
        const unsigned short* gsrc = Xq + (size_t)row * Cv + kt * 64 + srcslot * 8;
        __builtin_amdgcn_global_load_lds(
            (const __attribute__((address_space(1))) void*)gsrc,
            (__attribute__((address_space(3))) void*)((char*)Xt2 + buf * 8192 + seg * 1024),
            16, 0, 0);
      }
    };

    dmaQ(0, 0);
    dmaQ(1, 1);
    asm volatile("s_waitcnt vmcnt(2)" ::: "memory");
    SB0(); BARRIER(); SB0();
    for (int kt = 0; kt < 8; ++kt) {
      // (1) Bf loads FIRST (oldest in queue).
      bf16x8 Bf[2][4];
#pragma unroll
      for (int ks = 0; ks < 2; ++ks)
#pragma unroll
        for (int n = 0; n < 4; ++n)
          Bf[ks][n] = *(const bf16x8*)(
              WbF + (size_t)((((hsel * 8 + kt) * 2 + ks) * 8 + nq * 4 + n) * 64 + lane) * 8);
      SB0();
      // (2) DMA for kt+2 after.
      if (kt < 6) dmaQ(kt + 2, (kt + 2) & 3);   // buffer last read at MFMA(kt-2)
      SB0();
      const char* Xt = (const char*)Xt2 + (kt & 3) * 8192;
#pragma unroll
      for (int ks = 0; ks < 2; ++ks) {
        const int sx = ((ks * 4 + g) ^ (l15 & 7)) * 16;
        bf16x8 A[4];
#pragma unroll
        for (int m = 0; m < 4; ++m)
          A[m] = *(const bf16x8*)(Xt + (m * 16 + l15) * 128 + sx);
#pragma unroll
        for (int m = 0; m < 4; ++m)
#pragma unroll
          for (int n = 0; n < 4; ++n)
            acc[m][n] = __builtin_amdgcn_mfma_f32_16x16x32_bf16(A[m], Bf[ks][n],
                                                                acc[m][n], 0, 0, 0);
      }
      if (kt < 7) {
        SB0();
        if (kt < 6) {
          asm volatile("s_waitcnt vmcnt(2)" ::: "memory");  // kt+1 landed; kt+2 in flight
        } else {
          asm volatile("s_waitcnt vmcnt(0)" ::: "memory");
        }
        SB0(); BARRIER(); SB0();
      }
    }

    // Direct stores (16 query slabs, tiny). C/D map as above.
#pragma unroll
    for (int m = 0; m < 4; ++m) {
      const int pixr = pixq * 64 + m * 16 + g * 4;
#pragma unroll
      for (int n = 0; n < 4; ++n) {
        const int oc = nq * 64 + n * 16 + l15;
        if (hsel == 0) {
          unsigned short* p = Qb + ((size_t)sq * HWv + pixr) * DKv + oc;
#pragma unroll
          for (int r = 0; r < 4; ++r) p[(size_t)r * DKv] = f2b(acc[m][n][r]);
        } else {
          float* p = QVf + ((size_t)sq * HWv + pixr) * DVv + oc;
#pragma unroll
          for (int r = 0; r < 4; ++r) p[(size_t)r * DVv] = acc[m][n][r];
        }
      }
    }
  }
}

// ---------------------------------------------------------------------------
// attn_mfma (round-13 verified, best measured): WG = 4 waves x 16 qpix
// (grid 320); 32KB K/V chunk DMA'd once per WG, double-buffered
// global_load_lds; online softmax spans all ns; fused distance epilogue.
// ---------------------------------------------------------------------------
__global__ __launch_bounds__(256) void attn_mfma_kernel(
    const unsigned short* __restrict__ KbF, const unsigned short* __restrict__ VbF,
    const unsigned short* __restrict__ Qb, const float* __restrict__ QVf,
    float* __restrict__ out) {
  __shared__ __align__(16) char smem[74784];
  unsigned short* Klds = (unsigned short*)smem;             // [2][8192]
  unsigned short* Vlds = (unsigned short*)(smem + 32768);   // [2][8192]
  unsigned short* Plds = (unsigned short*)(smem + 65536);   // [4 wave][16][72]
  float* redbuf = (float*)(smem + 74752);                   // [4]

  const int L = blockIdx.x;
  const int bid = (L & 7) * 40 + (L >> 3);
  const int bn = bid >> 2, qh = bid & 3;
  const int b = bn / Nv;
  const int t = threadIdx.x;
  const int l = t & 63, wid = t >> 6;
  const int l15 = l & 15, g = l >> 4;
  const int qpix0 = qh * 64 + wid * 16;
  constexpr float C2 = 0.08838834764831845f * 1.4426950408889634f;

  bf16x8 qa[4];
#pragma unroll
  for (int kc = 0; kc < 4; ++kc)
    qa[kc] = *(const bf16x8*)(
        Qb + ((size_t)(b * HWv + qpix0 + l15)) * DKv + kc * 32 + g * 8);

  f32x4 oacc[8] = {};
  float mrow[4], lrow[4];
#pragma unroll
  for (int r = 0; r < 4; ++r) { mrow[r] = -3e38f; lrow[r] = 0.0f; }

  unsigned short* Pw = Plds + wid * 16 * 72;

  auto dma = [&](int c, int buf) {
    const int s2 = bn * Kv + (c >> 2);
    const int chunk = c & 3;
    const unsigned short* Kc = KbF + ((size_t)s2 * 4 + chunk) * 8192;
    const unsigned short* Vc = VbF + ((size_t)s2 * 4 + chunk) * 8192;
#pragma unroll
    for (int i = 0; i < 4; ++i) {
      const int seg = wid * 4 + i;
      __builtin_amdgcn_global_load_lds(
          (const __attribute__((address_space(1))) void*)(Kc + (size_t)(seg * 64 + l) * 8),
          (__attribute__((address_space(3))) void*)(Klds + (size_t)buf * 8192 + seg * 512),
          16, 0, 0);
      __builtin_amdgcn_global_load_lds(
          (const __attribute__((address_space(1))) void*)(Vc + (size_t)(seg * 64 + l) * 8),
          (__attribute__((address_space(3))) void*)(Vlds + (size_t)buf * 8192 + seg * 512),
          16, 0, 0);
    }
  };

  dma(0, 0);
  __syncthreads();
  for (int c = 0; c < 20; ++c) {
    const int cur = c & 1;
    if (c < 19) dma(c + 1, cur ^ 1);
    const unsigned short* Kc = Klds + (size_t)cur * 8192;
    const unsigned short* Vc = Vlds + (size_t)cur * 8192;

    f32x4 s4[4];
#pragma unroll
    for (int nc = 0; nc < 4; ++nc) {
      f32x4 sv = {};
#pragma unroll
      for (int kc = 0; kc < 4; ++kc) {
        bf16x8 kf = *(const bf16x8*)(Kc + (size_t)((nc * 4 + kc) * 64 + l) * 8);
        sv = __builtin_amdgcn_mfma_f32_16x16x32_bf16(qa[kc], kf, sv, 0, 0, 0);
      }
      s4[nc] = sv;
    }
    float pm[4];
#pragma unroll
    for (int r = 0; r < 4; ++r) {
      float v = s4[0][r];
#pragma unroll
      for (int nc = 1; nc < 4; ++nc) v = fmaxf(v, s4[nc][r]);
      pm[r] = v;
    }
#pragma unroll
    for (int off = 1; off <= 8; off <<= 1)
#pragma unroll
      for (int r = 0; r < 4; ++r) pm[r] = fmaxf(pm[r], __shfl_xor(pm[r], off));
    float sc[4];
#pragma unroll
    for (int r = 0; r < 4; ++r) {
      float mn = fmaxf(mrow[r], pm[r]);
      sc[r] = exp2f(C2 * (mrow[r] - mn));
      mrow[r] = mn;
      lrow[r] *= sc[r];
    }
#pragma unroll
    for (int d = 0; d < 8; ++d)
#pragma unroll
      for (int r = 0; r < 4; ++r) oacc[d][r] *= sc[r];
#pragma unroll
    for (int nc = 0; nc < 4; ++nc)
#pragma unroll
      for (int r = 0; r < 4; ++r) {
        float p = exp2f(C2 * (s4[nc][r] - mrow[r]));
        lrow[r] += p;
        Pw[(size_t)(g * 4 + r) * 72 + nc * 16 + l15] = f2b(p);
      }
#pragma unroll
    for (int kc2 = 0; kc2 < 2; ++kc2) {
      bf16x8 pa = *(const bf16x8*)(Pw + (size_t)l15 * 72 + kc2 * 32 + g * 8);
#pragma unroll
      for (int d = 0; d < 8; ++d) {
        bf16x8 vf = *(const bf16x8*)(Vc + (size_t)((kc2 * 8 + d) * 64 + l) * 8);
        oacc[d] = __builtin_amdgcn_mfma_f32_16x16x32_bf16(pa, vf, oacc[d], 0, 0, 0);
      }
    }
    __syncthreads();
  }

#pragma unroll
  for (int off = 1; off <= 8; off <<= 1)
#pragma unroll
    for (int r = 0; r < 4; ++r) lrow[r] += __shfl_xor(lrow[r], off);
  float linv[4];
#pragma unroll
  for (int r = 0; r < 4; ++r) linv[r] = 1.0f / lrow[r];

  float part = 0.0f;
#pragma unroll
  for (int d = 0; d < 8; ++d)
#pragma unroll
    for (int r = 0; r < 4; ++r) {
      float o = oacc[d][r] * linv[r];
      float qv = QVf[((size_t)(b * HWv + qpix0 + g * 4 + r)) * DVv + d * 16 + l15];
      float df = qv - o;
      part += df * df;
    }
#pragma unroll
  for (int off = 1; off <= 32; off <<= 1) part += __shfl_xor(part, off);
  if (l == 0) redbuf[wid] = part;
  __syncthreads();
  if (t == 0) {
    float tot = redbuf[0] + redbuf[1] + redbuf[2] + redbuf[3];
    atomicAdd(out + bn, -tot * (1.0f / HWv));
  }
}

// ---------------------------------------------------------------------------
extern "C" void kernel_launch(void* const* d_in, const int* in_sizes, int n_in,
                              void* d_out, int out_size, void* d_ws, size_t ws_size,
                              hipStream_t stream) {
  const float* query = (const float*)d_in[0];     // [B, C, H, W]
  const float* supports = (const float*)d_in[1];  // [B, N, K, C, H, W]
  const float* w_qk = (const float*)d_in[2];      // [DK, C]
  const float* w_v = (const float*)d_in[3];       // [DV, C]
  float* out = (float*)d_out;                     // [B, N]

  const size_t sz_kb = (size_t)NSUP * 4 * 8192 * 2;
  const size_t sz_vb = (size_t)NSUP * 4 * 8192 * 2;
  const size_t sz_qb = (size_t)Bv * HWv * DKv * 2;
  const size_t sz_qvf = (size_t)Bv * HWv * DVv * 4;
  const size_t sz_xb = (size_t)NSLAB * HWv * Cv * 2;
  const size_t sz_wb = (size_t)256 * Cv * 2;  // (kept for layout stability)

  char* p = (char*)d_ws;
  unsigned short* KbF = (unsigned short*)p;           p += sz_kb;
  unsigned short* VbF = (unsigned short*)p;           p += sz_vb;
  unsigned short* Qb = (unsigned short*)p;            p += sz_qb;
  float* QVf = (float*)p;                             p += sz_qvf;
  unsigned short* Xb = (unsigned short*)p;            p += sz_xb;
  p += sz_wb;  // (old row-major Wb slot, unused)
  unsigned short* WbF = (unsigned short*)p;

  prep_kernel<<<577, 256, 0, stream>>>(query, w_qk, w_v, WbF, Xb, out, out_size);
  proj_all_kernel<<<1664, 256, 0, stream>>>(supports, WbF, KbF, VbF, Xb, Qb, QVf);
  attn_mfma_kernel<<<Bv * Nv * 4, 256, 0, stream>>>(KbF, VbF, Qb, QVf, out);
}